// Round 15
// baseline (134.946 us; speedup 1.0000x reference)
//
#include <hip/hip_runtime.h>
#include <stdint.h>

typedef _Float16  f16;
typedef f16       f16x2  __attribute__((ext_vector_type(2)));
typedef f16       f16x8  __attribute__((ext_vector_type(8)));
typedef float     f32x16v __attribute__((ext_vector_type(16)));
typedef float     f32x4v  __attribute__((ext_vector_type(4)));
typedef uint32_t  u32x4v  __attribute__((ext_vector_type(4)));
typedef unsigned short u16;

__device__ __forceinline__ f32x16v mfma16h(u32x4v a, u32x4v b, f32x16v c) {
  return __builtin_amdgcn_mfma_f32_32x32x16_f16(
      __builtin_bit_cast(f16x8, a), __builtin_bit_cast(f16x8, b), c, 0, 0, 0);
}

// prep: W f32 [65][i=64][k=64] -> fragment-major f16 arrays (B-operand form).
// elem idx = jj*4096 + (ct*4+s)*512 + l*8 + e  (l = lane)
//   w1h: W[jj][ i=s*16+(l>>5)*8+e ][ k=ct*32+(l&31) ]
//   w2h: W[jj][ e_row=ct*32+(l&31) ][ k=s*16+(l>>5)*8+e ]
__global__ __launch_bounds__(256) void prep_w(const float* __restrict__ W,
                                              u16* __restrict__ w1h,
                                              u16* __restrict__ w2h) {
  __shared__ float Wl[4096];
  const int jj = blockIdx.x;
  const int t  = threadIdx.x;
  for (int idx = t; idx < 4096; idx += 256) Wl[idx] = W[jj * 4096 + idx];
  __syncthreads();
  for (int pq = t; pq < 512; pq += 256) {
    const int c2 = pq >> 6, l = pq & 63;
    const int ct = c2 >> 2, s = c2 & 3;
    const int rowA = ct * 32 + (l & 31);
    const int k0   = s * 16 + (l >> 5) * 8;
    u16 v1[8], v2[8];
    #pragma unroll
    for (int e = 0; e < 8; ++e) {
      v2[e] = __builtin_bit_cast(u16, (f16)Wl[rowA * 64 + k0 + e]);
      v1[e] = __builtin_bit_cast(u16, (f16)Wl[(k0 + e) * 64 + rowA]);
    }
    u32x4v pk1, pk2;
    #pragma unroll
    for (int q = 0; q < 4; ++q) {
      pk1[q] = (uint32_t)v1[2*q] | ((uint32_t)v1[2*q+1] << 16);
      pk2[q] = (uint32_t)v2[2*q] | ((uint32_t)v2[2*q+1] << 16);
    }
    *reinterpret_cast<u32x4v*>(w1h + jj * 4096 + pq * 8) = pk1;
    *reinterpret_cast<u32x4v*>(w2h + jj * 4096 + pq * 8) = pk2;
  }
}

// main: grid 256 (1 block/CU), 512 thr (8 waves = ct2 x sq4), BB=128.
// Single-buffer 16-j chunks (128 KB LDS): per pass only 5 barrier drains
// (vs 9-18 in earlier rounds). Per chunk: burst-issue 16 role-split
// global_load_lds per wave -> __syncthreads (the one drain) -> compute 16 j
// -> cheap __syncthreads. Proven compute core / combine from the 52us rounds.
__global__ __launch_bounds__(512) void rquad_main(
    const float* __restrict__ x, const float* __restrict__ g,
    const u16* __restrict__ w1h, const u16* __restrict__ w2h,
    float* __restrict__ out) {
  __shared__ __align__(16) u16      stage[16][4096];  // 128 KB (16 j x 8 KB)
  __shared__ __align__(16) uint32_t x1p[65 * 64];     // 16.6 KB packed x1

  float* vl = reinterpret_cast<float*>(&stage[0][0]); // [128][68] overlay

  const int t    = threadIdx.x;
  const int lane = t & 63;
  const int wv   = t >> 6;
  const int ct   = wv >> 2;        // output-col half
  const int sq   = wv & 3;         // K-quarter
  const int bl   = lane & 31;
  const int half = lane >> 5;
  const long base = (long)blockIdx.x * 128;
  const int fragoff = (ct * 4 + sq) * 512;   // this wave's 1KB frag (u16 elems)

  // prologue: x -> vl (coalesced) -> x1p[j][q] = (f16 x[q][j], f16 x[64+q][j])
  for (int q = t; q < 2048; q += 512) {
    const int row = q >> 4, c4 = (q & 15) * 4;
    *reinterpret_cast<f32x4v*>(&vl[row * 68 + c4]) =
        *reinterpret_cast<const f32x4v*>(&x[(base + row) * 64 + c4]);
  }
  __syncthreads();
  for (int idx = t; idx < 65 * 64; idx += 512) {
    const int j = idx >> 6, q = idx & 63;
    uint32_t val;
    if (j == 64) val = 0x3C003C00u;      // bias 1.0,1.0
    else {
      f16 a = (f16)vl[q * 68 + j];
      f16 b = (f16)vl[(64 + q) * 68 + j];
      val = (uint32_t)__builtin_bit_cast(u16, a) |
            ((uint32_t)__builtin_bit_cast(u16, b) << 16);
    }
    x1p[idx] = val;
  }
  // z init from g: K-slice i = sq*16 + half*8 + 0..7, per sample tile
  f16x2 z[4][4];
  #pragma unroll
  for (int tt = 0; tt < 4; ++tt) {
    const float* gp = g + (base + tt * 32 + bl) * 64 + sq * 16 + half * 8;
    f32x4v a = *reinterpret_cast<const f32x4v*>(gp);
    f32x4v b = *reinterpret_cast<const f32x4v*>(gp + 4);
    z[tt][0] = f16x2{(f16)a[0], (f16)a[1]};
    z[tt][1] = f16x2{(f16)a[2], (f16)a[3]};
    z[tt][2] = f16x2{(f16)b[0], (f16)b[1]};
    z[tt][3] = f16x2{(f16)b[2], (f16)b[3]};
  }
  __syncthreads();   // x1p ready; vl (stage) free for pass-1 staging

  f32x16v acc[4];

  auto compute_j = [&](int jl, int jglob) {
    u32x4v B = *reinterpret_cast<const u32x4v*>(&stage[jl][fragoff + lane * 8]);
    const uint32_t xw0 = x1p[jglob * 64 + bl];        // tiles 0(lo), 2(hi)
    const uint32_t xw1 = x1p[jglob * 64 + 32 + bl];   // tiles 1(lo), 3(hi)
    const f16x2 xp0 = __builtin_bit_cast(f16x2, xw0);
    const f16x2 xp1 = __builtin_bit_cast(f16x2, xw1);
    const f16x2 xb0 = f16x2{xp0[0], xp0[0]};
    const f16x2 xb1 = f16x2{xp1[0], xp1[0]};
    const f16x2 xb2 = f16x2{xp0[1], xp0[1]};
    const f16x2 xb3 = f16x2{xp1[1], xp1[1]};
    u32x4v a0, a1, a2, a3;
    #pragma unroll
    for (int q = 0; q < 4; ++q) {
      a0[q] = __builtin_bit_cast(uint32_t, f16x2(xb0 * z[0][q]));
      a1[q] = __builtin_bit_cast(uint32_t, f16x2(xb1 * z[1][q]));
      a2[q] = __builtin_bit_cast(uint32_t, f16x2(xb2 * z[2][q]));
      a3[q] = __builtin_bit_cast(uint32_t, f16x2(xb3 * z[3][q]));
    }
    acc[0] = mfma16h(a0, B, acc[0]);
    acc[1] = mfma16h(a1, B, acc[1]);
    acc[2] = mfma16h(a2, B, acc[2]);
    acc[3] = mfma16h(a3, B, acc[3]);
  };

  auto run_pass = [&](const u16* __restrict__ Wsrc) {
    #pragma unroll
    for (int tt = 0; tt < 4; ++tt)
      #pragma unroll
      for (int r = 0; r < 16; ++r) acc[tt][r] = 0.0f;
    for (int c = 0; c < 5; ++c) {
      const int nj = (c == 4) ? 1 : 16;
      const int j0 = c * 16;
      // burst-issue this wave's nj fragment loads
      for (int jl = 0; jl < nj; ++jl) {
        const u16* src = Wsrc + (size_t)(j0 + jl) * 4096 + fragoff + lane * 8;
        __builtin_amdgcn_global_load_lds(
            (const __attribute__((address_space(1))) void*)src,
            (__attribute__((address_space(3))) void*)(&stage[jl][fragoff]),
            16, 0, 0);
      }
      __syncthreads();                 // the one drain per chunk
      #pragma unroll 4
      for (int jl = 0; jl < nj; ++jl) compute_j(jl, j0 + jl);
      __syncthreads();                 // cheap: nothing outstanding
    }
  };

  auto combine = [&]() {
    for (int idx = t; idx < 128 * 68; idx += 512) vl[idx] = 0.0f;
    __syncthreads();
    #pragma unroll
    for (int tt = 0; tt < 4; ++tt)
      #pragma unroll
      for (int r = 0; r < 16; ++r) {
        const int rr = (r & 3) + 8 * (r >> 2) + 4 * half;
        atomicAdd(&vl[(tt * 32 + rr) * 68 + ct * 32 + bl], acc[tt][r]);
      }
    __syncthreads();
  };

  // ---------------- pass 1: v[b,k] ----------------
  run_pass(w1h);
  combine();
  // z <- v (f32 -> f16), K-slice k = sq*16 + half*8 + 0..7
  #pragma unroll
  for (int tt = 0; tt < 4; ++tt) {
    const float* vp = &vl[(tt * 32 + bl) * 68 + sq * 16 + half * 8];
    f32x4v a = *reinterpret_cast<const f32x4v*>(vp);
    f32x4v b = *reinterpret_cast<const f32x4v*>(vp + 4);
    z[tt][0] = f16x2{(f16)a[0], (f16)a[1]};
    z[tt][1] = f16x2{(f16)a[2], (f16)a[3]};
    z[tt][2] = f16x2{(f16)b[0], (f16)b[1]};
    z[tt][3] = f16x2{(f16)b[2], (f16)b[3]};
  }
  __syncthreads();   // vl consumed; stage free for pass-2 staging

  // ---------------- pass 2: out[b,e] ----------------
  run_pass(w2h);
  combine();
  for (int q = t; q < 2048; q += 512) {
    const int row = q >> 4, c4 = (q & 15) * 4;
    f32x4v v4 = *reinterpret_cast<const f32x4v*>(&vl[row * 68 + c4]);
    f32x4v o;
    o[0] = v4[0] * 0.125f; o[1] = v4[1] * 0.125f;
    o[2] = v4[2] * 0.125f; o[3] = v4[3] * 0.125f;
    *reinterpret_cast<f32x4v*>(&out[(base + row) * 64 + c4]) = o;
  }
}

extern "C" void kernel_launch(void* const* d_in, const int* in_sizes, int n_in,
                              void* d_out, int out_size, void* d_ws, size_t ws_size,
                              hipStream_t stream) {
  const float* x = (const float*)d_in[0];
  const float* g = (const float*)d_in[1];
  const float* W = (const float*)d_in[2];
  float* o = (float*)d_out;
  u16* w1h = (u16*)d_ws;                    // 65*4096 f16 = 520 KiB
  u16* w2h = w1h + 65 * 4096;               // another 520 KiB
  hipLaunchKernelGGL(prep_w, dim3(65), dim3(256), 0, stream, W, w1h, w2h);
  hipLaunchKernelGGL(rquad_main, dim3(256), dim3(512), 0, stream, x, g, w1h, w2h, o);
}

// Round 16
// 52.553 us; speedup vs baseline: 2.5678x; 2.5678x over previous
//
#include <hip/hip_runtime.h>
#include <stdint.h>

typedef _Float16  f16;
typedef f16       f16x2  __attribute__((ext_vector_type(2)));
typedef f16       f16x8  __attribute__((ext_vector_type(8)));
typedef float     f32x16v __attribute__((ext_vector_type(16)));
typedef float     f32x4v  __attribute__((ext_vector_type(4)));
typedef uint32_t  u32x4v  __attribute__((ext_vector_type(4)));
typedef unsigned short u16;

__device__ __forceinline__ f32x16v mfma16h(u32x4v a, u32x4v b, f32x16v c) {
  return __builtin_amdgcn_mfma_f32_32x32x16_f16(
      __builtin_bit_cast(f16x8, a), __builtin_bit_cast(f16x8, b), c, 0, 0, 0);
}

// prep: W f32 [65][i=64][k=64] -> fragment-major f16 arrays (B-operand form).
// elem idx = jj*4096 + (ct*4+s)*512 + l*8 + e  (l = lane)
//   w1h: W[jj][ i=s*16+(l>>5)*8+e ][ k=ct*32+(l&31) ]
//   w2h: W[jj][ e_row=ct*32+(l&31) ][ k=s*16+(l>>5)*8+e ]
__global__ __launch_bounds__(256) void prep_w(const float* __restrict__ W,
                                              u16* __restrict__ w1h,
                                              u16* __restrict__ w2h) {
  __shared__ float Wl[4096];
  const int jj = blockIdx.x;
  const int t  = threadIdx.x;
  for (int idx = t; idx < 4096; idx += 256) Wl[idx] = W[jj * 4096 + idx];
  __syncthreads();
  for (int pq = t; pq < 512; pq += 256) {
    const int c2 = pq >> 6, l = pq & 63;
    const int ct = c2 >> 2, s = c2 & 3;
    const int rowA = ct * 32 + (l & 31);
    const int k0   = s * 16 + (l >> 5) * 8;
    u16 v1[8], v2[8];
    #pragma unroll
    for (int e = 0; e < 8; ++e) {
      v2[e] = __builtin_bit_cast(u16, (f16)Wl[rowA * 64 + k0 + e]);
      v1[e] = __builtin_bit_cast(u16, (f16)Wl[(k0 + e) * 64 + rowA]);
    }
    u32x4v pk1, pk2;
    #pragma unroll
    for (int q = 0; q < 4; ++q) {
      pk1[q] = (uint32_t)v1[2*q] | ((uint32_t)v1[2*q+1] << 16);
      pk2[q] = (uint32_t)v2[2*q] | ((uint32_t)v2[2*q+1] << 16);
    }
    *reinterpret_cast<u32x4v*>(w1h + jj * 4096 + pq * 8) = pk1;
    *reinterpret_cast<u32x4v*>(w2h + jj * 4096 + pq * 8) = pk2;
  }
}

// main: R10 structure (52.3us) + per-block CHUNK-ORDER ROTATION to de-hotspot
// the L2: blocks visit W chunks with phase offset bid%nch, so concurrent
// requests spread over the whole 1MB array instead of one 32KB window.
// grid 256 (1 block/CU), 512 thr (8 waves = jq2 x p2 x ct2), BB=128.
// B s-chunks 0,1 staged in LDS (read-once), s-chunks 2,3 direct L2->VGPR.
__global__ __launch_bounds__(512, 2) void rquad_main(
    const float* __restrict__ x, const float* __restrict__ g,
    const u16* __restrict__ w1h, const u16* __restrict__ w2h,
    float* __restrict__ out) {
  __shared__ u16      stage[4][8192];   // 4 bufs x 16 KB (4j x [ct2][s2][1KB])
  __shared__ float    vl[128 * 68];     // 34.8 KB combine / repack buffer
  __shared__ uint32_t x1p[65 * 64];     // 16.6 KB packed x1 f16-pairs

  const int t    = threadIdx.x;
  const int lane = t & 63;
  const int wv   = t >> 6;
  const int jq   = wv >> 2;         // j-stream: 0 -> j 0..32, 1 -> j 33..64
  const int p    = (wv >> 1) & 1;   // sample half
  const int ct   = wv & 1;          // output-column half
  const int bl   = lane & 31;
  const int half = lane >> 5;
  const long base = (long)blockIdx.x * 128;
  const int rot0 = (int)(blockIdx.x % 9u);   // stream-0 chunk rotation (9 chunks)
  const int rot1 = (int)(blockIdx.x % 8u);   // stream-1 chunk rotation (8 chunks)

  // physical chunk for logical index ci in this wave's stream
  auto pchunk = [&](int ci) {
    if (jq == 0) { int pc = ci + rot0; return (pc >= 9) ? pc - 9 : pc; }
    else         { int pc = ci + rot1; return (pc >= 8) ? pc - 8 : pc; }
  };

  // prologue: coalesced x -> vl, then repack to x1p (pairs (r, r+32) per p)
  for (int q = t; q < 2048; q += 512) {
    const int row = q >> 4, c4 = (q & 15) * 4;
    *reinterpret_cast<f32x4v*>(&vl[row * 68 + c4]) =
        *reinterpret_cast<const f32x4v*>(&x[(base + row) * 64 + c4]);
  }
  __syncthreads();
  for (int idx = t; idx < 65 * 64; idx += 512) {
    const int j = idx >> 6, q = idx & 63, pp = q >> 5, qq = q & 31;
    uint32_t val;
    if (j == 64) val = 0x3C003C00u;                  // bias row = 1.0,1.0
    else {
      f16 a = (f16)vl[(pp * 64 + qq) * 68 + j];
      f16 b = (f16)vl[(pp * 64 + 32 + qq) * 68 + j];
      val = (uint32_t)__builtin_bit_cast(u16, a) |
            ((uint32_t)__builtin_bit_cast(u16, b) << 16);
    }
    x1p[idx] = val;
  }

  const int r0 = p * 64 + bl, r1 = r0 + 32;

  // z init from g (pass-1 K-side)
  f16x2 z0[4][4], z1[4][4];
  #pragma unroll
  for (int s = 0; s < 4; ++s) {
    const float* gp0 = g + (base + r0) * 64 + s * 16 + half * 8;
    const float* gp1 = g + (base + r1) * 64 + s * 16 + half * 8;
    f32x4v a = *reinterpret_cast<const f32x4v*>(gp0);
    f32x4v b = *reinterpret_cast<const f32x4v*>(gp0 + 4);
    f32x4v c = *reinterpret_cast<const f32x4v*>(gp1);
    f32x4v d = *reinterpret_cast<const f32x4v*>(gp1 + 4);
    z0[s][0] = f16x2{(f16)a[0],(f16)a[1]}; z0[s][1] = f16x2{(f16)a[2],(f16)a[3]};
    z0[s][2] = f16x2{(f16)b[0],(f16)b[1]}; z0[s][3] = f16x2{(f16)b[2],(f16)b[3]};
    z1[s][0] = f16x2{(f16)c[0],(f16)c[1]}; z1[s][1] = f16x2{(f16)c[2],(f16)c[3]};
    z1[s][2] = f16x2{(f16)d[0],(f16)d[1]}; z1[s][3] = f16x2{(f16)d[2],(f16)d[3]};
  }

  f32x16v acc0, acc1;

  auto stage_chunk = [&](const u16* __restrict__ Wsrc, int ci) {
    const int nch = (jq == 0) ? 9 : 8;
    if (ci >= nch) return;
    const int pc  = pchunk(ci);
    const int j0  = (jq == 0) ? pc * 4 : 33 + pc * 4;
    const int njs = (jq == 0 && pc == 8) ? 1 : 4;
    const int buf = jq * 2 + (ci & 1);
    #pragma unroll
    for (int u = 0; u < 2; ++u) {
      const int jl = 2 * p + u;
      if (jl < njs) {
        #pragma unroll
        for (int s = 0; s < 2; ++s) {
          const u16* src = Wsrc + (size_t)(j0 + jl) * 4096 + ct * 2048 + s * 512 + lane * 8;
          __builtin_amdgcn_global_load_lds(
              (const __attribute__((address_space(1))) void*)src,
              (__attribute__((address_space(3))) void*)(
                  &stage[buf][jl * 2048 + ct * 1024 + s * 512 + lane * 8]),
              16, 0, 0);
        }
      }
    }
  };

  auto compute_j = [&](const u16* __restrict__ Wsrc, int buf, int jl, int jglob) {
    // s=2,3 straight from L2 to regs (issued first, used last)
    const u16* gp = Wsrc + (size_t)jglob * 4096 + ct * 2048 + 1024 + lane * 8;
    u32x4v B2 = *reinterpret_cast<const u32x4v*>(gp);
    u32x4v B3 = *reinterpret_cast<const u32x4v*>(gp + 512);
    // s=0,1 from LDS (staged previous step)
    const u16* sb = &stage[buf][jl * 2048 + ct * 1024 + lane * 8];
    u32x4v B0 = *reinterpret_cast<const u32x4v*>(sb);
    u32x4v B1 = *reinterpret_cast<const u32x4v*>(sb + 512);
    const uint32_t xw = x1p[jglob * 64 + p * 32 + bl];
    const f16 xlo = __builtin_bit_cast(f16, (u16)(xw & 0xffffu));
    const f16 xhi = __builtin_bit_cast(f16, (u16)(xw >> 16));
    const f16x2 xx0 = f16x2{xlo, xlo}, xx1 = f16x2{xhi, xhi};
    u32x4v Bs[4] = {B0, B1, B2, B3};
    #pragma unroll
    for (int s = 0; s < 4; ++s) {
      u32x4v a0, a1;
      #pragma unroll
      for (int q = 0; q < 4; ++q) {
        a0[q] = __builtin_bit_cast(uint32_t, f16x2(xx0 * z0[s][q]));
        a1[q] = __builtin_bit_cast(uint32_t, f16x2(xx1 * z1[s][q]));
      }
      acc0 = mfma16h(a0, Bs[s], acc0);
      acc1 = mfma16h(a1, Bs[s], acc1);
    }
  };

  auto run_pass = [&](const u16* __restrict__ Wsrc) {
    #pragma unroll
    for (int r = 0; r < 16; ++r) { acc0[r] = 0.0f; acc1[r] = 0.0f; }
    stage_chunk(Wsrc, 0);
    __syncthreads();
    for (int st = 0; st < 9; ++st) {
      stage_chunk(Wsrc, st + 1);
      const int buf = jq * 2 + (st & 1);
      if (st < 8 || jq == 0) {
        if (jq == 1 && st >= 8) { /* unreachable */ }
        const int pc = pchunk(st);
        if (jq == 1 && st >= 8) {}
        if (!(jq == 1 && st >= 8)) {
          const int jbase = (jq == 0) ? pc * 4 : 33 + pc * 4;
          const int nj = (jq == 0 && pc == 8) ? 1 : 4;
          for (int jl = 0; jl < nj; ++jl) compute_j(Wsrc, buf, jl, jbase + jl);
        }
      }
      __syncthreads();
    }
  };

  __syncthreads();  // x1p ready

  // ---------------- pass 1: v[b,k] ----------------
  run_pass(w1h);

  if (jq == 0) {
    #pragma unroll
    for (int r = 0; r < 16; ++r) {
      const int rr = (r & 3) + 8 * (r >> 2) + 4 * half;
      vl[(p * 64 + rr) * 68 + ct * 32 + bl]      = acc0[r];
      vl[(p * 64 + 32 + rr) * 68 + ct * 32 + bl] = acc1[r];
    }
  }
  __syncthreads();
  if (jq == 1) {
    #pragma unroll
    for (int r = 0; r < 16; ++r) {
      const int rr = (r & 3) + 8 * (r >> 2) + 4 * half;
      vl[(p * 64 + rr) * 68 + ct * 32 + bl]      += acc0[r];
      vl[(p * 64 + 32 + rr) * 68 + ct * 32 + bl] += acc1[r];
    }
  }
  __syncthreads();
  // z <- v (f32 -> f16)
  #pragma unroll
  for (int s = 0; s < 4; ++s) {
    const float* vp0 = &vl[r0 * 68 + s * 16 + half * 8];
    const float* vp1 = &vl[r1 * 68 + s * 16 + half * 8];
    f32x4v a = *reinterpret_cast<const f32x4v*>(vp0);
    f32x4v b = *reinterpret_cast<const f32x4v*>(vp0 + 4);
    f32x4v c = *reinterpret_cast<const f32x4v*>(vp1);
    f32x4v d = *reinterpret_cast<const f32x4v*>(vp1 + 4);
    z0[s][0] = f16x2{(f16)a[0],(f16)a[1]}; z0[s][1] = f16x2{(f16)a[2],(f16)a[3]};
    z0[s][2] = f16x2{(f16)b[0],(f16)b[1]}; z0[s][3] = f16x2{(f16)b[2],(f16)b[3]};
    z1[s][0] = f16x2{(f16)c[0],(f16)c[1]}; z1[s][1] = f16x2{(f16)c[2],(f16)c[3]};
    z1[s][2] = f16x2{(f16)d[0],(f16)d[1]}; z1[s][3] = f16x2{(f16)d[2],(f16)d[3]};
  }
  // pass-2's first barrier orders vl-reads vs later writes

  // ---------------- pass 2: out[b,e] ----------------
  run_pass(w2h);

  if (jq == 0) {
    #pragma unroll
    for (int r = 0; r < 16; ++r) {
      const int rr = (r & 3) + 8 * (r >> 2) + 4 * half;
      vl[(p * 64 + rr) * 68 + ct * 32 + bl]      = acc0[r];
      vl[(p * 64 + 32 + rr) * 68 + ct * 32 + bl] = acc1[r];
    }
  }
  __syncthreads();
  if (jq == 1) {
    #pragma unroll
    for (int r = 0; r < 16; ++r) {
      const int rr = (r & 3) + 8 * (r >> 2) + 4 * half;
      vl[(p * 64 + rr) * 68 + ct * 32 + bl]      += acc0[r];
      vl[(p * 64 + 32 + rr) * 68 + ct * 32 + bl] += acc1[r];
    }
  }
  __syncthreads();
  for (int q = t; q < 2048; q += 512) {
    const int row = q >> 4, c4 = (q & 15) * 4;
    f32x4v v4 = *reinterpret_cast<const f32x4v*>(&vl[row * 68 + c4]);
    f32x4v o;
    o[0] = v4[0] * 0.125f; o[1] = v4[1] * 0.125f;
    o[2] = v4[2] * 0.125f; o[3] = v4[3] * 0.125f;
    *reinterpret_cast<f32x4v*>(&out[(base + row) * 64 + c4]) = o;
  }
}

extern "C" void kernel_launch(void* const* d_in, const int* in_sizes, int n_in,
                              void* d_out, int out_size, void* d_ws, size_t ws_size,
                              hipStream_t stream) {
  const float* x = (const float*)d_in[0];
  const float* g = (const float*)d_in[1];
  const float* W = (const float*)d_in[2];
  float* o = (float*)d_out;
  u16* w1h = (u16*)d_ws;                    // 65*4096 f16 = 520 KiB
  u16* w2h = w1h + 65 * 4096;               // another 520 KiB
  hipLaunchKernelGGL(prep_w, dim3(65), dim3(256), 0, stream, W, w1h, w2h);
  hipLaunchKernelGGL(rquad_main, dim3(256), dim3(512), 0, stream, x, g, w1h, w2h, o);
}